// Round 15
// baseline (48.401 us; speedup 1.0000x reference)
//
#include <hip/hip_runtime.h>
#include <hip/hip_fp16.h>

// KA-conv: out[b,o,h,w] = sum_m P_om(v) / (1+|Q_om(v)|), v = zero-padded patch
// value, m = c*9+ki*3+kj, M=144. ~75.5M rational evals.
//
// R15: f32-scalar/f32-pk/f16-pk all plateau at 32-34us -> NOT issue-bound;
// R4/R9 counters show 35-46% VALU idle even at max TLP -> wave-convoyed
// memory latency. This round attacks latency structure, keeping R14's f16
// pipeline: (a) VMEM 12 -> 4 loads/c-iter: load center column only (4 padded
// rows), build 3 packed row-pairs, get left/right neighbor PAIRS via
// __shfl_up/__shfl_down of the packed u32 (padding makes shuffled-in edges
// zero; only lanes 0/63 cndmask); (b) FULL unroll of the c-loop so the
// scheduler can hoist loads/s_loads across iterations (unroll-2 produced a
// strict per-pair convoy). Geometry/prep unchanged from R14.

constexpr int Bn = 4, Cin = 16, Hh = 64, Ww = 64, Oc = 32, Mtot = 144;
constexpr int PW = 66;                       // padded plane width/height
constexpr size_t WSX_FLOATS = (size_t)Bn * Cin * PW * PW;   // 278784
constexpr int NREC = Oc * Mtot;              // 4608 coefficient records

// ---- prep: pad x planes (f32) + broadcast-f16 coefficient records ----
__global__ __launch_bounds__(256)
void ka_prep_kernel(const float* __restrict__ x,
                    const float* __restrict__ nums,
                    const float* __restrict__ denoms,
                    float* __restrict__ wsf) {
  const int blk = blockIdx.x;
  if (blk < Bn * Cin) {
    const float* __restrict__ xp = x + (size_t)blk * Hh * Ww;
    float* __restrict__ wp_ = wsf + (size_t)blk * PW * PW;
    for (int i = threadIdx.x; i < PW * PW; i += 256) {
      const int hp = i / PW, wq = i % PW;
      const bool in = (hp >= 1) & (hp <= Hh) & (wq >= 1) & (wq <= Ww);
      wp_[i] = in ? xp[(hp - 1) * Ww + (wq - 1)] : 0.f;
    }
  } else {
    // one record per thread: 12 u32s = [A0..A5, C1..C4, pad, pad], each u32
    // a broadcast pair (h<<16)|h of the f16-rounded coefficient.
    const int idx = (blk - Bn * Cin) * 256 + threadIdx.x;
    if (idx < NREC) {
      const float* __restrict__ a = nums + (size_t)idx * 6;
      const float* __restrict__ c = denoms + (size_t)idx * 4;
      unsigned int* __restrict__ r =
          (unsigned int*)(wsf + WSX_FLOATS) + (size_t)idx * 12;
      #pragma unroll
      for (int k = 0; k < 6; ++k) {
        const unsigned short h = __half_as_ushort(__float2half_rn(a[k]));
        r[k] = ((unsigned int)h << 16) | h;
      }
      #pragma unroll
      for (int k = 0; k < 4; ++k) {
        const unsigned short h = __half_as_ushort(__float2half_rn(c[k]));
        r[6 + k] = ((unsigned int)h << 16) | h;
      }
      r[10] = 0u; r[11] = 0u;
    }
  }
}

__device__ __forceinline__ __half2 u2h2(unsigned int u) {
  union { unsigned int u; __half2 h; } cv; cv.u = u; return cv.h;
}
__device__ __forceinline__ int h22i(__half2 h) {
  union { int i; __half2 h; } cv; cv.h = h; return cv.i;
}
__device__ __forceinline__ __half2 i2h2(int i) {
  union { int i; __half2 h; } cv; cv.i = i; return cv.h;
}

__global__ __launch_bounds__(256, 4)
void ka_conv_kernel(const float* __restrict__ wsf, float* __restrict__ out) {
  const int tid = threadIdx.x;
  const int n   = blockIdx.x;
  const int ht  = n & 7;                  // 8 height tiles of 8 rows (low bits)
  const int o   = __builtin_amdgcn_readfirstlane((n >> 3) & 31);  // uniform
  const int b   = n >> 8;                 // batch

  const int w  = tid & 63;                // lane == output column
  const int rg = tid >> 6;                // rowgroup 0..3
  const int h0 = ht * 8 + rg * 2;         // this thread's 2 output rows

  const float* __restrict__ xb = wsf + (size_t)b * Cin * PW * PW;
  const unsigned int* __restrict__ coef =
      (const unsigned int*)(wsf + WSX_FLOATS) + (size_t)o * Mtot * 12;

  // 3 column accumulators (half2 lanes = rows h0, h0+1)
  __half2 acc0 = __floats2half2_rn(0.f, 0.f);
  __half2 acc1 = acc0, acc2 = acc0;
  const __half2 one2 = __floats2half2_rn(1.f, 1.f);
  const __half2 z2   = __floats2half2_rn(0.f, 0.f);
  const bool wlv = (w > 0), wrv = (w < 63);

#define TAP(t, vp, accK) do {                                                  \
    const unsigned int* __restrict__ rr = pc + (t) * 12;                       \
    const __half2 v_ = (vp);                                                   \
    __half2 nm = __hfma2(u2h2(rr[5]), v_, u2h2(rr[4]));                        \
    nm = __hfma2(nm, v_, u2h2(rr[3]));                                         \
    nm = __hfma2(nm, v_, u2h2(rr[2]));                                         \
    nm = __hfma2(nm, v_, u2h2(rr[1]));                                         \
    nm = __hfma2(nm, v_, u2h2(rr[0]));                                         \
    __half2 dp = __hfma2(u2h2(rr[9]), v_, u2h2(rr[8]));                        \
    dp = __hfma2(dp, v_, u2h2(rr[7]));                                         \
    dp = __hfma2(dp, v_, u2h2(rr[6]));                                         \
    dp = __hmul2(dp, v_);                                                      \
    const __half2 dn = __hadd2(one2, __habs2(dp));                             \
    accK = __hfma2(nm, h2rcp(dn), accK);                                       \
  } while (0)

  #pragma unroll
  for (int c = 0; c < Cin; ++c) {
    const float* __restrict__ xc = xb + (size_t)c * (PW * PW);
    // center column only: padded col (w+1) == original col w; rows h0..h0+3
    const int base = h0 * PW + (w + 1);
    const float x0 = xc[base + 0 * PW];
    const float x1 = xc[base + 1 * PW];
    const float x2 = xc[base + 2 * PW];
    const float x3 = xc[base + 3 * PW];

    // packed center row-pairs (rows h0-1+ki, h0+ki in original coords)
    const __half2 qc0 = __floats2half2_rn(x0, x1);   // ki=0
    const __half2 qc1 = __floats2half2_rn(x1, x2);   // ki=1
    const __half2 qc2 = __floats2half2_rn(x2, x3);   // ki=2

    // neighbors via wave shuffles of the PACKED pairs; padded edge value is
    // exactly 0, so only lanes 0/63 need the mask. Shuffles run
    // unconditionally (full exec), then select.
    const __half2 sl0 = i2h2(__shfl_up(h22i(qc0), 1));
    const __half2 sl1 = i2h2(__shfl_up(h22i(qc1), 1));
    const __half2 sl2 = i2h2(__shfl_up(h22i(qc2), 1));
    const __half2 sr0 = i2h2(__shfl_down(h22i(qc0), 1));
    const __half2 sr1 = i2h2(__shfl_down(h22i(qc1), 1));
    const __half2 sr2 = i2h2(__shfl_down(h22i(qc2), 1));
    const __half2 ql0 = wlv ? sl0 : z2, ql1 = wlv ? sl1 : z2, ql2 = wlv ? sl2 : z2;
    const __half2 qr0 = wrv ? sr0 : z2, qr1 = wrv ? sr1 : z2, qr2 = wrv ? sr2 : z2;

    const unsigned int* __restrict__ pc = coef + (size_t)c * 9 * 12;
    TAP(0, ql0, acc0);  TAP(1, qc0, acc1);  TAP(2, qr0, acc2);
    TAP(3, ql1, acc0);  TAP(4, qc1, acc1);  TAP(5, qr1, acc2);
    TAP(6, ql2, acc0);  TAP(7, qc2, acc1);  TAP(8, qr2, acc2);
  }
#undef TAP

  // final sum in f32
  const float2 f0 = __half22float2(acc0);
  const float2 f1 = __half22float2(acc1);
  const float2 f2 = __half22float2(acc2);
  float* op = out + ((size_t)(b * Oc + o) * Hh + h0) * Ww + w;
  op[0]  = f0.x + f1.x + f2.x;
  op[Ww] = f0.y + f1.y + f2.y;
}

extern "C" void kernel_launch(void* const* d_in, const int* in_sizes, int n_in,
                              void* d_out, int out_size, void* d_ws, size_t ws_size,
                              hipStream_t stream) {
  const float* x      = (const float*)d_in[0];
  const float* nums   = (const float*)d_in[1];
  const float* denoms = (const float*)d_in[2];
  float* out          = (float*)d_out;
  float* ws           = (float*)d_ws;

  const int padBlocks = Bn * Cin;
  const int recBlocks = (NREC + 255) / 256;
  ka_prep_kernel<<<padBlocks + recBlocks, 256, 0, stream>>>(x, nums, denoms, ws);

  // main: blockIdx = (b*32 + o)*8 + ht  (ht in low bits)
  ka_conv_kernel<<<Bn * Oc * 8, 256, 0, stream>>>(ws, out);
}

// Round 16
// 45.859 us; speedup vs baseline: 1.0554x; 1.0554x over previous
//
#include <hip/hip_runtime.h>
#include <hip/hip_fp16.h>

// KA-conv: out[b,o,h,w] = sum_m P_om(v) / (1+|Q_om(v)|), v = zero-padded patch
// value, m = c*9+ki*3+kj, M=144. ~75.5M rational evals.
//
// R16: the untested matrix cell = 8 waves/SIMD AND >=4-eval amortization.
// (R6/R9: 8 waves lifted VALUBusy 54->75% but 1-row threads inflated instrs;
// R11's c-split was mis-sized at 2 blocks/CU.) Design: c-QUARTER split —
// block = 256 thr = 4 quarters x 64 cols; thread = 4 output rows x 1 col x
// 4 channels; grid 2048 x 256 = 524288 threads = 8 blocks/CU = 32 waves/CU
// IF VGPR<=64 (launch_bounds(256,4); R8 showed min-waves=8 forces spill).
// f16-pk TAPs: 2 half2 Horner chains per tap (4 evals, ILP 2). Padded-x
// prep (no masks, 18 plain loads/c-iter); broadcast-f16 coeff records
// (s_load, SGPR-direct pk operands). Cross-quarter reduce: 4KB LDS, one
// barrier, fixed-order adds (deterministic). Shuffle experiments reverted
// (R7 wrong, R15 slow).

constexpr int Bn = 4, Cin = 16, Hh = 64, Ww = 64, Oc = 32, Mtot = 144;
constexpr int PW = 66;                       // padded plane width/height
constexpr size_t WSX_FLOATS = (size_t)Bn * Cin * PW * PW;   // 278784
constexpr int NREC = Oc * Mtot;              // 4608 coefficient records

// ---- prep: pad x planes (f32) + broadcast-f16 coefficient records ----
__global__ __launch_bounds__(256)
void ka_prep_kernel(const float* __restrict__ x,
                    const float* __restrict__ nums,
                    const float* __restrict__ denoms,
                    float* __restrict__ wsf) {
  const int blk = blockIdx.x;
  if (blk < Bn * Cin) {
    const float* __restrict__ xp = x + (size_t)blk * Hh * Ww;
    float* __restrict__ wp_ = wsf + (size_t)blk * PW * PW;
    for (int i = threadIdx.x; i < PW * PW; i += 256) {
      const int hp = i / PW, wq = i % PW;
      const bool in = (hp >= 1) & (hp <= Hh) & (wq >= 1) & (wq <= Ww);
      wp_[i] = in ? xp[(hp - 1) * Ww + (wq - 1)] : 0.f;
    }
  } else {
    // 12 u32s per record = [A0..A5, C1..C4, pad, pad], each u32 = (h<<16)|h
    const int idx = (blk - Bn * Cin) * 256 + threadIdx.x;
    if (idx < NREC) {
      const float* __restrict__ a = nums + (size_t)idx * 6;
      const float* __restrict__ c = denoms + (size_t)idx * 4;
      unsigned int* __restrict__ r =
          (unsigned int*)(wsf + WSX_FLOATS) + (size_t)idx * 12;
      #pragma unroll
      for (int k = 0; k < 6; ++k) {
        const unsigned short h = __half_as_ushort(__float2half_rn(a[k]));
        r[k] = ((unsigned int)h << 16) | h;
      }
      #pragma unroll
      for (int k = 0; k < 4; ++k) {
        const unsigned short h = __half_as_ushort(__float2half_rn(c[k]));
        r[6 + k] = ((unsigned int)h << 16) | h;
      }
      r[10] = 0u; r[11] = 0u;
    }
  }
}

__device__ __forceinline__ __half2 u2h2(unsigned int u) {
  union { unsigned int u; __half2 h; } cv; cv.u = u; return cv.h;
}

__global__ __launch_bounds__(256, 4)
void ka_conv_kernel(const float* __restrict__ wsf, float* __restrict__ out) {
  __shared__ float part[1024];            // [quarter][row0..3][w]

  const int tid = threadIdx.x;
  const int n   = blockIdx.x;
  const int ht  = n & 15;                 // 16 tiles of 4 rows (low bits)
  const int o   = __builtin_amdgcn_readfirstlane((n >> 4) & 31);  // uniform
  const int b   = n >> 9;                 // batch

  const int w  = tid & 63;                // lane == output column
  const int q  = tid >> 6;                // c-quarter 0..3 (== wave id)
  const int h0 = ht * 4;                  // block's 4 output rows

  const float* __restrict__ xb = wsf + (size_t)b * Cin * PW * PW;
  const unsigned int* __restrict__ coef =
      (const unsigned int*)(wsf + WSX_FLOATS) + (size_t)o * Mtot * 12;

  // 6 accumulators: per column (3) x row-pair (A: rows h0,h0+1; B: h0+2,h0+3)
  __half2 a0A = __floats2half2_rn(0.f, 0.f);
  __half2 a1A = a0A, a2A = a0A, a0B = a0A, a1B = a0A, a2B = a0A;
  const __half2 one2 = __floats2half2_rn(1.f, 1.f);

  // one tap slot t: 4 evals as two packed Horner chains (ILP 2).
  // rr[k] = wave-uniform s_load -> single-SGPR operand of each v_pk_fma_f16.
#define TAP4(t, vA, vB, accA, accB) do {                                       \
    const unsigned int* __restrict__ rr = pc + (t) * 12;                       \
    __half2 nA = __hfma2(u2h2(rr[5]), (vA), u2h2(rr[4]));                      \
    __half2 nB = __hfma2(u2h2(rr[5]), (vB), u2h2(rr[4]));                      \
    nA = __hfma2(nA, (vA), u2h2(rr[3]));  nB = __hfma2(nB, (vB), u2h2(rr[3])); \
    nA = __hfma2(nA, (vA), u2h2(rr[2]));  nB = __hfma2(nB, (vB), u2h2(rr[2])); \
    nA = __hfma2(nA, (vA), u2h2(rr[1]));  nB = __hfma2(nB, (vB), u2h2(rr[1])); \
    nA = __hfma2(nA, (vA), u2h2(rr[0]));  nB = __hfma2(nB, (vB), u2h2(rr[0])); \
    __half2 dA = __hfma2(u2h2(rr[9]), (vA), u2h2(rr[8]));                      \
    __half2 dB = __hfma2(u2h2(rr[9]), (vB), u2h2(rr[8]));                      \
    dA = __hfma2(dA, (vA), u2h2(rr[7]));  dB = __hfma2(dB, (vB), u2h2(rr[7])); \
    dA = __hfma2(dA, (vA), u2h2(rr[6]));  dB = __hfma2(dB, (vB), u2h2(rr[6])); \
    dA = __hmul2(dA, (vA));               dB = __hmul2(dB, (vB));              \
    const __half2 eA = __hadd2(one2, __habs2(dA));                             \
    const __half2 eB = __hadd2(one2, __habs2(dB));                             \
    accA = __hfma2(nA, h2rcp(eA), accA);                                       \
    accB = __hfma2(nB, h2rcp(eB), accB);                                       \
  } while (0)

  #pragma unroll 2
  for (int ci = 0; ci < 4; ++ci) {
    const int c = q * 4 + ci;
    const float* __restrict__ xc = xb + (size_t)c * (PW * PW);
    const int base = h0 * PW + w;          // padded row h0, padded col w

    // 18 plain coalesced loads: padded rows h0..h0+5, padded cols w..w+2
    float x0j0 = xc[base + 0 * PW + 0], x0j1 = xc[base + 0 * PW + 1], x0j2 = xc[base + 0 * PW + 2];
    float x1j0 = xc[base + 1 * PW + 0], x1j1 = xc[base + 1 * PW + 1], x1j2 = xc[base + 1 * PW + 2];
    float x2j0 = xc[base + 2 * PW + 0], x2j1 = xc[base + 2 * PW + 1], x2j2 = xc[base + 2 * PW + 2];
    float x3j0 = xc[base + 3 * PW + 0], x3j1 = xc[base + 3 * PW + 1], x3j2 = xc[base + 3 * PW + 2];
    float x4j0 = xc[base + 4 * PW + 0], x4j1 = xc[base + 4 * PW + 1], x4j2 = xc[base + 4 * PW + 2];
    float x5j0 = xc[base + 5 * PW + 0], x5j1 = xc[base + 5 * PW + 1], x5j2 = xc[base + 5 * PW + 2];

    // packed row-pairs per column: h{k,k+1}[j]
    const __half2 h01j0 = __floats2half2_rn(x0j0, x1j0);
    const __half2 h01j1 = __floats2half2_rn(x0j1, x1j1);
    const __half2 h01j2 = __floats2half2_rn(x0j2, x1j2);
    const __half2 h12j0 = __floats2half2_rn(x1j0, x2j0);
    const __half2 h12j1 = __floats2half2_rn(x1j1, x2j1);
    const __half2 h12j2 = __floats2half2_rn(x1j2, x2j2);
    const __half2 h23j0 = __floats2half2_rn(x2j0, x3j0);
    const __half2 h23j1 = __floats2half2_rn(x2j1, x3j1);
    const __half2 h23j2 = __floats2half2_rn(x2j2, x3j2);
    const __half2 h34j0 = __floats2half2_rn(x3j0, x4j0);
    const __half2 h34j1 = __floats2half2_rn(x3j1, x4j1);
    const __half2 h34j2 = __floats2half2_rn(x3j2, x4j2);
    const __half2 h45j0 = __floats2half2_rn(x4j0, x5j0);
    const __half2 h45j1 = __floats2half2_rn(x4j1, x5j1);
    const __half2 h45j2 = __floats2half2_rn(x4j2, x5j2);

    const unsigned int* __restrict__ pc = coef + (size_t)c * 9 * 12;
    // tap t = ki*3 + j: pair A = h{ki,ki+1}[j], pair B = h{ki+2,ki+3}[j]
    TAP4(0, h01j0, h23j0, a0A, a0B);
    TAP4(1, h01j1, h23j1, a1A, a1B);
    TAP4(2, h01j2, h23j2, a2A, a2B);
    TAP4(3, h12j0, h34j0, a0A, a0B);
    TAP4(4, h12j1, h34j1, a1A, a1B);
    TAP4(5, h12j2, h34j2, a2A, a2B);
    TAP4(6, h23j0, h45j0, a0A, a0B);
    TAP4(7, h23j1, h45j1, a1A, a1B);
    TAP4(8, h23j2, h45j2, a2A, a2B);
  }
#undef TAP4

  // per-thread column sum -> f32, stash in LDS: part[q][row][w]
  const float2 fA = __half22float2(__hadd2(__hadd2(a0A, a1A), a2A));
  const float2 fB = __half22float2(__hadd2(__hadd2(a0B, a1B), a2B));
  part[q * 256 +   0 + w] = fA.x;   // row h0+0
  part[q * 256 +  64 + w] = fA.y;   // row h0+1
  part[q * 256 + 128 + w] = fB.x;   // row h0+2
  part[q * 256 + 192 + w] = fB.y;   // row h0+3
  __syncthreads();

  // 256 threads finalize: fixed-order cross-quarter add (deterministic)
  if (tid < 256) {
    const int row = tid >> 6, ww = tid & 63;
    const int s = row * 64 + ww;
    const float v = ((part[s] + part[256 + s]) + part[512 + s]) + part[768 + s];
    out[((size_t)(b * Oc + o) * Hh + h0 + row) * Ww + ww] = v;
  }
}

extern "C" void kernel_launch(void* const* d_in, const int* in_sizes, int n_in,
                              void* d_out, int out_size, void* d_ws, size_t ws_size,
                              hipStream_t stream) {
  const float* x      = (const float*)d_in[0];
  const float* nums   = (const float*)d_in[1];
  const float* denoms = (const float*)d_in[2];
  float* out          = (float*)d_out;
  float* ws           = (float*)d_ws;

  const int padBlocks = Bn * Cin;
  const int recBlocks = (NREC + 255) / 256;
  ka_prep_kernel<<<padBlocks + recBlocks, 256, 0, stream>>>(x, nums, denoms, ws);

  // main: blockIdx = ((b*32 + o)*16 + ht), ht in low bits
  ka_conv_kernel<<<Bn * Oc * 16, 256, 0, stream>>>(ws, out);
}

// Round 17
// 31.625 us; speedup vs baseline: 1.5305x; 1.4501x over previous
//
#include <hip/hip_runtime.h>
#include <hip/hip_fp16.h>

// KA-conv: out[b,o,h,w] = sum_m P_om(v) / (1+|Q_om(v)|), v = zero-padded patch
// value, m = c*9+ki*3+kj, M=144. ~75.5M rational evals.
//
// R17: R16's SGPR_Count=32 exposed the real bug — q = tid>>6 is runtime-
// wave-uniform but LLVM marks it divergent, so the coefficient address chain
// went VGPR and every tap issued ~10 per-lane VMEM loads (idle exploded;
// busy-time itself was the best yet at ~15us). Fix: q via readfirstlane ->
// the whole chain is provably SGPR -> s_load with imm offsets, 4-eval
// amortized. Everything else identical to R16: 256-thr block = 4 c-quarter
// waves x 64 cols, thread = 4 rows x 4 channels, f16-pk dual Horner chains,
// padded-x + broadcast-f16 coeff records in ws, 4KB LDS cross-quarter
// reduce, grid 2048 (8 blocks/CU at VGPR<=64).

constexpr int Bn = 4, Cin = 16, Hh = 64, Ww = 64, Oc = 32, Mtot = 144;
constexpr int PW = 66;                       // padded plane width/height
constexpr size_t WSX_FLOATS = (size_t)Bn * Cin * PW * PW;   // 278784
constexpr int NREC = Oc * Mtot;              // 4608 coefficient records

// ---- prep: pad x planes (f32) + broadcast-f16 coefficient records ----
__global__ __launch_bounds__(256)
void ka_prep_kernel(const float* __restrict__ x,
                    const float* __restrict__ nums,
                    const float* __restrict__ denoms,
                    float* __restrict__ wsf) {
  const int blk = blockIdx.x;
  if (blk < Bn * Cin) {
    const float* __restrict__ xp = x + (size_t)blk * Hh * Ww;
    float* __restrict__ wp_ = wsf + (size_t)blk * PW * PW;
    for (int i = threadIdx.x; i < PW * PW; i += 256) {
      const int hp = i / PW, wq = i % PW;
      const bool in = (hp >= 1) & (hp <= Hh) & (wq >= 1) & (wq <= Ww);
      wp_[i] = in ? xp[(hp - 1) * Ww + (wq - 1)] : 0.f;
    }
  } else {
    // 12 u32s per record = [A0..A5, C1..C4, pad, pad], each u32 = (h<<16)|h
    const int idx = (blk - Bn * Cin) * 256 + threadIdx.x;
    if (idx < NREC) {
      const float* __restrict__ a = nums + (size_t)idx * 6;
      const float* __restrict__ c = denoms + (size_t)idx * 4;
      unsigned int* __restrict__ r =
          (unsigned int*)(wsf + WSX_FLOATS) + (size_t)idx * 12;
      #pragma unroll
      for (int k = 0; k < 6; ++k) {
        const unsigned short h = __half_as_ushort(__float2half_rn(a[k]));
        r[k] = ((unsigned int)h << 16) | h;
      }
      #pragma unroll
      for (int k = 0; k < 4; ++k) {
        const unsigned short h = __half_as_ushort(__float2half_rn(c[k]));
        r[6 + k] = ((unsigned int)h << 16) | h;
      }
      r[10] = 0u; r[11] = 0u;
    }
  }
}

__device__ __forceinline__ __half2 u2h2(unsigned int u) {
  union { unsigned int u; __half2 h; } cv; cv.u = u; return cv.h;
}

__global__ __launch_bounds__(256, 4)
void ka_conv_kernel(const float* __restrict__ wsf, float* __restrict__ out) {
  __shared__ float part[1024];            // [quarter][row0..3][w]

  const int tid = threadIdx.x;
  const int n   = blockIdx.x;
  const int ht  = n & 15;                 // 16 tiles of 4 rows (low bits)
  const int o   = __builtin_amdgcn_readfirstlane((n >> 4) & 31);  // uniform
  const int b   = n >> 9;                 // batch

  const int w  = tid & 63;                // lane == output column
  // q is wave-uniform at runtime; readfirstlane makes it PROVABLY uniform so
  // the coefficient address chain scalarizes to s_load (R16: SGPR=32 bug).
  const int q  = __builtin_amdgcn_readfirstlane(tid >> 6);   // c-quarter 0..3
  const int h0 = ht * 4;                  // block's 4 output rows

  const float* __restrict__ xb = wsf + (size_t)b * Cin * PW * PW;
  const unsigned int* __restrict__ coef =
      (const unsigned int*)(wsf + WSX_FLOATS) + (size_t)o * Mtot * 12;

  // 6 accumulators: per column (3) x row-pair (A: rows h0,h0+1; B: h0+2,h0+3)
  __half2 a0A = __floats2half2_rn(0.f, 0.f);
  __half2 a1A = a0A, a2A = a0A, a0B = a0A, a1B = a0A, a2B = a0A;
  const __half2 one2 = __floats2half2_rn(1.f, 1.f);

  // one tap slot t: 4 evals as two packed Horner chains (ILP 2).
  // rr[k] = wave-uniform s_load -> single-SGPR operand of each v_pk_fma_f16.
#define TAP4(t, vA, vB, accA, accB) do {                                       \
    const unsigned int* __restrict__ rr = pc + (t) * 12;                       \
    __half2 nA = __hfma2(u2h2(rr[5]), (vA), u2h2(rr[4]));                      \
    __half2 nB = __hfma2(u2h2(rr[5]), (vB), u2h2(rr[4]));                      \
    nA = __hfma2(nA, (vA), u2h2(rr[3]));  nB = __hfma2(nB, (vB), u2h2(rr[3])); \
    nA = __hfma2(nA, (vA), u2h2(rr[2]));  nB = __hfma2(nB, (vB), u2h2(rr[2])); \
    nA = __hfma2(nA, (vA), u2h2(rr[1]));  nB = __hfma2(nB, (vB), u2h2(rr[1])); \
    nA = __hfma2(nA, (vA), u2h2(rr[0]));  nB = __hfma2(nB, (vB), u2h2(rr[0])); \
    __half2 dA = __hfma2(u2h2(rr[9]), (vA), u2h2(rr[8]));                      \
    __half2 dB = __hfma2(u2h2(rr[9]), (vB), u2h2(rr[8]));                      \
    dA = __hfma2(dA, (vA), u2h2(rr[7]));  dB = __hfma2(dB, (vB), u2h2(rr[7])); \
    dA = __hfma2(dA, (vA), u2h2(rr[6]));  dB = __hfma2(dB, (vB), u2h2(rr[6])); \
    dA = __hmul2(dA, (vA));               dB = __hmul2(dB, (vB));              \
    const __half2 eA = __hadd2(one2, __habs2(dA));                             \
    const __half2 eB = __hadd2(one2, __habs2(dB));                             \
    accA = __hfma2(nA, h2rcp(eA), accA);                                       \
    accB = __hfma2(nB, h2rcp(eB), accB);                                       \
  } while (0)

  #pragma unroll 2
  for (int ci = 0; ci < 4; ++ci) {
    const int c = q * 4 + ci;              // uniform (q is SGPR)
    const float* __restrict__ xc = xb + (size_t)c * (PW * PW);
    const int base = h0 * PW + w;          // padded row h0, padded col w

    // 18 plain coalesced loads: padded rows h0..h0+5, padded cols w..w+2
    float x0j0 = xc[base + 0 * PW + 0], x0j1 = xc[base + 0 * PW + 1], x0j2 = xc[base + 0 * PW + 2];
    float x1j0 = xc[base + 1 * PW + 0], x1j1 = xc[base + 1 * PW + 1], x1j2 = xc[base + 1 * PW + 2];
    float x2j0 = xc[base + 2 * PW + 0], x2j1 = xc[base + 2 * PW + 1], x2j2 = xc[base + 2 * PW + 2];
    float x3j0 = xc[base + 3 * PW + 0], x3j1 = xc[base + 3 * PW + 1], x3j2 = xc[base + 3 * PW + 2];
    float x4j0 = xc[base + 4 * PW + 0], x4j1 = xc[base + 4 * PW + 1], x4j2 = xc[base + 4 * PW + 2];
    float x5j0 = xc[base + 5 * PW + 0], x5j1 = xc[base + 5 * PW + 1], x5j2 = xc[base + 5 * PW + 2];

    // packed row-pairs per column: h{k,k+1}[j]
    const __half2 h01j0 = __floats2half2_rn(x0j0, x1j0);
    const __half2 h01j1 = __floats2half2_rn(x0j1, x1j1);
    const __half2 h01j2 = __floats2half2_rn(x0j2, x1j2);
    const __half2 h12j0 = __floats2half2_rn(x1j0, x2j0);
    const __half2 h12j1 = __floats2half2_rn(x1j1, x2j1);
    const __half2 h12j2 = __floats2half2_rn(x1j2, x2j2);
    const __half2 h23j0 = __floats2half2_rn(x2j0, x3j0);
    const __half2 h23j1 = __floats2half2_rn(x2j1, x3j1);
    const __half2 h23j2 = __floats2half2_rn(x2j2, x3j2);
    const __half2 h34j0 = __floats2half2_rn(x3j0, x4j0);
    const __half2 h34j1 = __floats2half2_rn(x3j1, x4j1);
    const __half2 h34j2 = __floats2half2_rn(x3j2, x4j2);
    const __half2 h45j0 = __floats2half2_rn(x4j0, x5j0);
    const __half2 h45j1 = __floats2half2_rn(x4j1, x5j1);
    const __half2 h45j2 = __floats2half2_rn(x4j2, x5j2);

    const unsigned int* __restrict__ pc = coef + (size_t)c * 9 * 12;  // SGPR
    // tap t = ki*3 + j: pair A = h{ki,ki+1}[j], pair B = h{ki+2,ki+3}[j]
    TAP4(0, h01j0, h23j0, a0A, a0B);
    TAP4(1, h01j1, h23j1, a1A, a1B);
    TAP4(2, h01j2, h23j2, a2A, a2B);
    TAP4(3, h12j0, h34j0, a0A, a0B);
    TAP4(4, h12j1, h34j1, a1A, a1B);
    TAP4(5, h12j2, h34j2, a2A, a2B);
    TAP4(6, h23j0, h45j0, a0A, a0B);
    TAP4(7, h23j1, h45j1, a1A, a1B);
    TAP4(8, h23j2, h45j2, a2A, a2B);
  }
#undef TAP4

  // per-thread column sum -> f32, stash in LDS: part[q][row][w]
  const float2 fA = __half22float2(__hadd2(__hadd2(a0A, a1A), a2A));
  const float2 fB = __half22float2(__hadd2(__hadd2(a0B, a1B), a2B));
  part[q * 256 +   0 + w] = fA.x;   // row h0+0
  part[q * 256 +  64 + w] = fA.y;   // row h0+1
  part[q * 256 + 128 + w] = fB.x;   // row h0+2
  part[q * 256 + 192 + w] = fB.y;   // row h0+3
  __syncthreads();

  // finalize: fixed-order cross-quarter add (deterministic)
  {
    const int row = tid >> 6, ww = tid & 63;
    const int s = row * 64 + ww;
    const float v = ((part[s] + part[256 + s]) + part[512 + s]) + part[768 + s];
    out[((size_t)(b * Oc + o) * Hh + h0 + row) * Ww + ww] = v;
  }
}

extern "C" void kernel_launch(void* const* d_in, const int* in_sizes, int n_in,
                              void* d_out, int out_size, void* d_ws, size_t ws_size,
                              hipStream_t stream) {
  const float* x      = (const float*)d_in[0];
  const float* nums   = (const float*)d_in[1];
  const float* denoms = (const float*)d_in[2];
  float* out          = (float*)d_out;
  float* ws           = (float*)d_ws;

  const int padBlocks = Bn * Cin;
  const int recBlocks = (NREC + 255) / 256;
  ka_prep_kernel<<<padBlocks + recBlocks, 256, 0, stream>>>(x, nums, denoms, ws);

  // main: blockIdx = ((b*32 + o)*16 + ht), ht in low bits
  ka_conv_kernel<<<Bn * Oc * 16, 256, 0, stream>>>(ws, out);
}